// Round 8
// baseline (254.080 us; speedup 1.0000x reference)
//
#include <hip/hip_runtime.h>
#include <hip/hip_fp16.h>
#include <math.h>

#define PI_F 3.14159265358979323846f

typedef __attribute__((ext_vector_type(8))) short bh8;    // 8 bf16 in 4 VGPRs
typedef __attribute__((ext_vector_type(4))) float f32x4;  // MFMA accumulator

#define LAG1 12      // LAG-1
#define BB   32
#define NN   1200
#define KPAD 1216    // 1200 padded to 19*64
#define NPAD 1216
#define NITER 19     // KPAD / 64
#define KS0   10     // k-iters in split-K slice 0 (slice 1 gets 9)
#define LDSW  72     // LDS row stride in shorts — 144B, 16B-aligned (70 broke b128 alignment)
#define NFLAG (19 * LAG1)   // one ticket per (bn,lag) pair

// X row layout (interleaved for in-register group fusion):
//   row = lag*96 + (b>>4)*48 + g*16 + (b&15),  g: 0=A(Tout) 1=old(TN) 2=new(T0)

// prep block ranges
#define ROW_I4 (KPAD / 8)          // 152 int4 per X row
#define PA_BLK 228                 // A copy: 384 rows * 152 int4 / 256
#define PB_BLK 150                 // TI gather: 32*1200 / 256
#define PD_BLK 6                   // zero-pad g1/g2 rows cols 1200..1215
#define PC_BLK 1444                // WT transpose 38*38
#define PE_BLK 1                   // coef + flag zeroing
#define PREP_BLOCKS (PA_BLK + PB_BLK + PD_BLK + PC_BLK + PE_BLK)

__device__ __forceinline__ unsigned short f2bf(float f) {
    unsigned int u = __float_as_uint(f);
    u = (u + 0x7fffu + ((u >> 16) & 1u)) >> 16;
    return (unsigned short)u;
}

__device__ __forceinline__ float gamma_fn_dev(float x) {
    if (x > 0.0f) return expf(lgammaf(x));
    return PI_F / (sinf(PI_F * x) * expf(lgammaf(1.0f - x)));
}

// ---- prep: X stack (interleaved rows) + pads + WT transpose + coefs + flags ----
__global__ __launch_bounds__(256) void prep_kernel(const float* __restrict__ A,
                                                   const float* __restrict__ TI,
                                                   const float* __restrict__ WW,
                                                   const float* __restrict__ alpha,
                                                   const float* __restrict__ fract,
                                                   unsigned short* __restrict__ X,
                                                   unsigned short* __restrict__ WT,
                                                   float* __restrict__ coef,
                                                   int* __restrict__ flags) {
    __shared__ float tile[32][33];
    const int bid = blockIdx.x;
    const int t = threadIdx.x;

    if (bid < PA_BLK) {
        // part A: A[lag*32+b, k] -> X row lag*96 + (b>>4)*48 + (b&15)
        int idx = bid * 256 + t;                 // 0..58367
        int ra = idx / ROW_I4;                   // 0..383 (= lag*32+b)
        int c8 = idx - ra * ROW_I4;              // 0..151
        int k = c8 * 8;
        int row = (ra >> 5) * 96 + ((ra >> 4) & 1) * 48 + (ra & 15);
        unsigned short v[8];
        #pragma unroll
        for (int u = 0; u < 8; u++) {
            int kk = k + u;
            v[u] = (kk < NN) ? f2bf(A[ra * NN + kk]) : (unsigned short)0;
        }
        *(int4*)&X[row * KPAD + k] = *(int4*)v;
    } else if (bid < PA_BLK + PB_BLK) {
        // part B: TI gather; thread = (b, i)
        int idx = (bid - PA_BLK) * 256 + t;      // 0..38399
        int b = idx / NN, i = idx - b * NN;
        const float* p = TI + (size_t)(b * NN + i) * 26 + 1;  // [...,lg,1]
        float vals[13];
        #pragma unroll
        for (int lg = 0; lg < 13; lg++) vals[lg] = p[lg * 2];
        int rbase = (b >> 4) * 48 + (b & 15);
        #pragma unroll
        for (int lag = 0; lag < LAG1; lag++) {
            X[(lag * 96 + rbase + 16) * KPAD + i] = f2bf(vals[lag]);      // g1 old -> TN
            X[(lag * 96 + rbase + 32) * KPAD + i] = f2bf(vals[lag + 1]);  // g2 new -> T0
        }
    } else if (bid < PA_BLK + PB_BLK + PD_BLK) {
        // part D: zero-pad cols 1200..1215 for the 768 g1/g2 rows
        int idx = (bid - PA_BLK - PB_BLK) * 256 + t;  // 0..1535
        if (idx < 768 * 2) {
            int pr = idx >> 1, h = idx & 1;
            int lag = pr / 64, rem = pr - lag * 64;
            int half = rem >> 5, gi = (rem >> 4) & 1, b16 = rem & 15;
            int row = lag * 96 + half * 48 + 16 + gi * 16 + b16;
            int4 z = {0, 0, 0, 0};
            *(int4*)&X[row * KPAD + 1200 + h * 8] = z;
        }
    } else if (bid < PA_BLK + PB_BLK + PD_BLK + PC_BLK) {
        // part C: WT[j*NPAD+i] = bf16(WW[i*NN+j]), zero-padded
        int cb = bid - (PA_BLK + PB_BLK + PD_BLK);
        int bx = cb % 38, by = cb / 38;
        int i0 = by * 32, j0 = bx * 32;
        int tx = t & 31, ty = t >> 5;            // 32 x 8
        #pragma unroll
        for (int s = 0; s < 32; s += 8) {
            int i = i0 + ty + s, j = j0 + tx;
            tile[ty + s][tx] = (i < NN && j < NN) ? WW[i * NN + j] : 0.0f;
        }
        __syncthreads();
        #pragma unroll
        for (int s = 0; s < 32; s += 8) {
            int j = j0 + ty + s, i = i0 + tx;
            WT[j * NPAD + i] = f2bf(tile[tx][ty + s]);
        }
    } else {
        // part E: per-lag coefficients + zero the split-K tickets (ws is 0xAA-poisoned!)
        if (t < NFLAG) flags[t] = 0;
        int lag = t;
        if (lag < LAG1) {
            float a = alpha[lag], f = fract[lag];
            float ga1 = expf(lgammaf(a + 1.0f));
            float belta = 0.0f;
            const float gk[4] = {1.0f, 1.0f, 2.0f, 6.0f};
            #pragma unroll
            for (int kk = 0; kk < 4; kk++)
                belta += ga1 / (gk[kk] * gamma_fn_dev(a - (float)kk + 1.0f));
            coef[lag]      = 2.0f * powf(3.0f, f);                  // e0
            coef[12 + lag] = ga1 / (6.0f * gamma_fn_dev(a - 2.0f)); // c2
            coef[24 + lag] = 1.0f / belta;                          // 1/belta
        }
    }
}

// ---- split-K GEMM with last-finisher fused epilogue ----
// Block (bn, ks, lag): R5's proven K-loop (runtime trip count — measured best).
// Both blocks of a (bn,lag) pair store fp16 partials; the ticket's second
// finisher reads the OTHER slice's partials (own accs still in registers),
// applies tanh + coefficient algebra, writes `out`. No combine kernel.
__global__ __launch_bounds__(512) void gemm_splitk(const unsigned short* __restrict__ X,
                                                   const unsigned short* __restrict__ WT,
                                                   __half* __restrict__ P,
                                                   int* __restrict__ flags,
                                                   const float* __restrict__ coef,
                                                   const float* __restrict__ lambd,
                                                   const float* __restrict__ l,
                                                   float* __restrict__ out) {
    __shared__ unsigned short Xs[2][96 * LDSW];
    __shared__ unsigned short Bs[2][64 * LDSW];
    __shared__ int sec_flag;
    const int bn = blockIdx.x, ks = blockIdx.y, lag = blockIdx.z;
    const int t = threadIdx.x;
    const int wave = t >> 6, lane = t & 63;
    const int l15 = lane & 15, quad = lane >> 4;
    const int mh = wave >> 2, nq = wave & 3;
    const int n0 = bn * 64;
    const int itStart = ks ? KS0 : 0;
    const int itEnd   = ks ? NITER : KS0;

    // staging addresses: X rows 0..63 by all 512, rows 64..95 by t<256 (wave-uniform)
    const int row0 = t >> 3, c80 = (t & 7) * 8;
    const unsigned short* gx0 = X + (size_t)(lag * 96 + row0) * KPAD + c80;
    const unsigned short* gx1 = X + (size_t)(lag * 96 + 64 + row0) * KPAD + c80;
    const unsigned short* gb0 = WT + (size_t)(n0 + row0) * NPAD + c80;
    const int lx0 = row0 * LDSW + c80;
    const int lx1 = (64 + row0) * LDSW + c80;

    int4 xr0, xr1, br0;
    {
        const int k0 = itStart * 64;
        xr0 = *(const int4*)(gx0 + k0);
        if (t < 256) xr1 = *(const int4*)(gx1 + k0);
        br0 = *(const int4*)(gb0 + k0);
    }

    f32x4 acc[3] = {};   // g0=Tout, g1=TN(old), g2=T0(new) partial sums

    for (int it = itStart; it < itEnd; ++it) {
        const int p = (it - itStart) & 1;
        *(int4*)&Xs[p][lx0] = xr0;
        if (t < 256) *(int4*)&Xs[p][lx1] = xr1;
        *(int4*)&Bs[p][lx0] = br0;
        __syncthreads();
        if (it + 1 < itEnd) {
            const int k1 = (it + 1) * 64;
            xr0 = *(const int4*)(gx0 + k1);
            if (t < 256) xr1 = *(const int4*)(gx1 + k1);
            br0 = *(const int4*)(gb0 + k1);
        }
        #pragma unroll
        for (int kh = 0; kh < 2; kh++) {
            bh8 bfrag = *(const bh8*)&Bs[p][(nq * 16 + l15) * LDSW + kh * 32 + quad * 8];
            #pragma unroll
            for (int g = 0; g < 3; g++) {
                bh8 afrag = *(const bh8*)&Xs[p][(mh * 48 + g * 16 + l15) * LDSW + kh * 32 + quad * 8];
                acc[g] = __builtin_amdgcn_mfma_f32_16x16x32_bf16(afrag, bfrag, acc[g], 0, 0, 0);
            }
        }
        // single barrier per iter is safe: write(i+1) targets the buffer read at
        // i-1; every wave's MFMA(i-1) precedes its write(i) -> barrier(i) orders it.
    }

    // store own partials as fp16 (C/D layout: col=lane&15, row=quad*4+reg)
    const int j = n0 + nq * 16 + l15;
    {
        __half* Pk = P + (size_t)ks * (1152 * NN);
        if (j < NN) {
            #pragma unroll
            for (int g = 0; g < 3; g++) {
                int rowb = lag * 96 + mh * 48 + g * 16 + quad * 4;
                #pragma unroll
                for (int r = 0; r < 4; r++)
                    Pk[(size_t)(rowb + r) * NN + j] = __float2half(acc[g][r]);
            }
        }
    }
    __threadfence();                       // release: partials before ticket
    if (t == 0) sec_flag = atomicAdd(&flags[bn * LAG1 + lag], 1);
    __syncthreads();
    if (sec_flag == 1) {                   // exactly one block per pair: last finisher
        __threadfence();                   // acquire: other slice's stores visible
        const __half* Po = P + (size_t)(1 - ks) * (1152 * NN);
        if (j < NN) {
            const int jm = j % 200;
            const float lv  = l[lag * 200 + jm];
            const float lam = lambd[lag * 200 + jm];
            const float e0 = coef[lag], c2 = coef[12 + lag], ib = coef[24 + lag];
            #pragma unroll
            for (int r = 0; r < 4; r++) {
                int rb_ = lag * 96 + mh * 48 + quad * 4 + r;
                float s0 = acc[0][r] + __half2float(Po[(size_t)rb_ * NN + j]);
                float s1 = acc[1][r] + __half2float(Po[(size_t)(rb_ + 16) * NN + j]);
                float s2 = acc[2][r] + __half2float(Po[(size_t)(rb_ + 32) * NN + j]);
                int b = mh * 16 + quad * 4 + r;
                out[(size_t)(b * LAG1 + lag) * NN + j] =
                    lam * ib * (e0 * tanhf(-s0) + 3.0f * lv * (tanhf(-s2) + c2 * tanhf(-s1)));
            }
        }
    }
}

extern "C" void kernel_launch(void* const* d_in, const int* in_sizes, int n_in,
                              void* d_out, int out_size, void* d_ws, size_t ws_size,
                              hipStream_t stream) {
    const float* A     = (const float*)d_in[0];
    const float* WW    = (const float*)d_in[1];
    const float* TI    = (const float*)d_in[2];
    const float* alpha = (const float*)d_in[3];
    const float* fract = (const float*)d_in[4];
    const float* lambd = (const float*)d_in[5];
    const float* l     = (const float*)d_in[6];
    float* out = (float*)d_out;

    unsigned short* X  = (unsigned short*)d_ws;      // 1152*1216 bf16
    unsigned short* WT = X + 1152 * KPAD;            // 1216*1216 bf16
    __half* P    = (__half*)(WT + (size_t)NPAD * NPAD); // 2 * 1152*1200 fp16 partials
    float* coef  = (float*)(P + (size_t)2 * 1152 * NN); // 36 f32
    int*   flags = (int*)(coef + 36);                   // 228 tickets (zeroed by prep)

    prep_kernel<<<PREP_BLOCKS, 256, 0, stream>>>(A, TI, WW, alpha, fract, X, WT, coef, flags);
    gemm_splitk<<<dim3(19, 2, LAG1), 512, 0, stream>>>(X, WT, P, flags, coef, lambd, l, out);
}

// Round 9
// 104.586 us; speedup vs baseline: 2.4294x; 2.4294x over previous
//
#include <hip/hip_runtime.h>
#include <math.h>

#define PI_F 3.14159265358979323846f

typedef __attribute__((ext_vector_type(8))) short bh8;    // 8 bf16 in 4 VGPRs
typedef __attribute__((ext_vector_type(4))) float f32x4;  // MFMA accumulator
typedef __attribute__((ext_vector_type(4))) _Float16 h4;  // 4 fp16 = 8B

#define LAG1 12      // LAG-1
#define BB   32
#define NN   1200
#define KPAD 1216    // 1200 padded to 19*64
#define NPAD 1216
#define NITER 19     // KPAD / 64
#define KS0   10     // k-iters in split-K slice 0 (slice 1 gets 9)
#define LDSW  72     // LDS row stride in shorts — 144B, 16B-aligned (70 broke b128 alignment)

// X row layout (interleaved for in-register group fusion):
//   row = lag*96 + (b>>4)*48 + g*16 + (b&15),  g: 0=A(Tout) 1=old(TN) 2=new(T0)

// prep block ranges
#define ROW_I4 (KPAD / 8)          // 152 int4 per X row
#define PA_BLK 228                 // A copy: 384 rows * 152 int4 / 256
#define PB_BLK 150                 // TI gather: 32*1200 / 256
#define PD_BLK 6                   // zero-pad g1/g2 rows cols 1200..1215
#define PC_BLK 1444                // WT transpose 38*38
#define PE_BLK 1                   // coef
#define PREP_BLOCKS (PA_BLK + PB_BLK + PD_BLK + PC_BLK + PE_BLK)

__device__ __forceinline__ unsigned short f2bf(float f) {
    unsigned int u = __float_as_uint(f);
    u = (u + 0x7fffu + ((u >> 16) & 1u)) >> 16;
    return (unsigned short)u;
}

__device__ __forceinline__ float gamma_fn_dev(float x) {
    if (x > 0.0f) return expf(lgammaf(x));
    return PI_F / (sinf(PI_F * x) * expf(lgammaf(1.0f - x)));
}

// ---- prep: X stack (interleaved rows) + pads + WT transpose + coefs ----
__global__ __launch_bounds__(256) void prep_kernel(const float* __restrict__ A,
                                                   const float* __restrict__ TI,
                                                   const float* __restrict__ WW,
                                                   const float* __restrict__ alpha,
                                                   const float* __restrict__ fract,
                                                   unsigned short* __restrict__ X,
                                                   unsigned short* __restrict__ WT,
                                                   float* __restrict__ coef) {
    __shared__ float tile[32][33];
    const int bid = blockIdx.x;
    const int t = threadIdx.x;

    if (bid < PA_BLK) {
        // part A: A[lag*32+b, k] -> X row lag*96 + (b>>4)*48 + (b&15)
        int idx = bid * 256 + t;                 // 0..58367
        int ra = idx / ROW_I4;                   // 0..383 (= lag*32+b)
        int c8 = idx - ra * ROW_I4;              // 0..151
        int k = c8 * 8;
        int row = (ra >> 5) * 96 + ((ra >> 4) & 1) * 48 + (ra & 15);
        unsigned short v[8];
        #pragma unroll
        for (int u = 0; u < 8; u++) {
            int kk = k + u;
            v[u] = (kk < NN) ? f2bf(A[ra * NN + kk]) : (unsigned short)0;
        }
        *(int4*)&X[row * KPAD + k] = *(int4*)v;
    } else if (bid < PA_BLK + PB_BLK) {
        // part B: TI gather; thread = (b, i)
        int idx = (bid - PA_BLK) * 256 + t;      // 0..38399
        int b = idx / NN, i = idx - b * NN;
        const float* p = TI + (size_t)(b * NN + i) * 26 + 1;  // [...,lg,1]
        float vals[13];
        #pragma unroll
        for (int lg = 0; lg < 13; lg++) vals[lg] = p[lg * 2];
        int rbase = (b >> 4) * 48 + (b & 15);
        #pragma unroll
        for (int lag = 0; lag < LAG1; lag++) {
            X[(lag * 96 + rbase + 16) * KPAD + i] = f2bf(vals[lag]);      // g1 old -> TN
            X[(lag * 96 + rbase + 32) * KPAD + i] = f2bf(vals[lag + 1]);  // g2 new -> T0
        }
    } else if (bid < PA_BLK + PB_BLK + PD_BLK) {
        // part D: zero-pad cols 1200..1215 for the 768 g1/g2 rows
        int idx = (bid - PA_BLK - PB_BLK) * 256 + t;  // 0..1535
        if (idx < 768 * 2) {
            int pr = idx >> 1, h = idx & 1;
            int lag = pr / 64, rem = pr - lag * 64;
            int half = rem >> 5, gi = (rem >> 4) & 1, b16 = rem & 15;
            int row = lag * 96 + half * 48 + 16 + gi * 16 + b16;
            int4 z = {0, 0, 0, 0};
            *(int4*)&X[row * KPAD + 1200 + h * 8] = z;
        }
    } else if (bid < PA_BLK + PB_BLK + PD_BLK + PC_BLK) {
        // part C: WT[j*NPAD+i] = bf16(WW[i*NN+j]), zero-padded
        int cb = bid - (PA_BLK + PB_BLK + PD_BLK);
        int bx = cb % 38, by = cb / 38;
        int i0 = by * 32, j0 = bx * 32;
        int tx = t & 31, ty = t >> 5;            // 32 x 8
        #pragma unroll
        for (int s = 0; s < 32; s += 8) {
            int i = i0 + ty + s, j = j0 + tx;
            tile[ty + s][tx] = (i < NN && j < NN) ? WW[i * NN + j] : 0.0f;
        }
        __syncthreads();
        #pragma unroll
        for (int s = 0; s < 32; s += 8) {
            int j = j0 + ty + s, i = i0 + tx;
            WT[j * NPAD + i] = f2bf(tile[tx][ty + s]);
        }
    } else {
        // part E: per-lag coefficients
        int lag = t;
        if (lag < LAG1) {
            float a = alpha[lag], f = fract[lag];
            float ga1 = expf(lgammaf(a + 1.0f));
            float belta = 0.0f;
            const float gk[4] = {1.0f, 1.0f, 2.0f, 6.0f};
            #pragma unroll
            for (int kk = 0; kk < 4; kk++)
                belta += ga1 / (gk[kk] * gamma_fn_dev(a - (float)kk + 1.0f));
            coef[lag]      = 2.0f * powf(3.0f, f);                  // e0
            coef[12 + lag] = ga1 / (6.0f * gamma_fn_dev(a - 2.0f)); // c2
            coef[24 + lag] = 1.0f / belta;                          // 1/belta
        }
    }
}

// ---- split-K GEMM: 512 threads, 8 waves; wave = (mh = b-half, nq = 16-col slice) ----
// Block (bn, ks, lag). Stores raw fp16 partial sums to P[ks] (no tanh here).
// EXACT R5 K-loop (runtime trip count — measured best; R7 unroll & R8 fences both lost).
__global__ __launch_bounds__(512) void gemm_splitk(const unsigned short* __restrict__ X,
                                                   const unsigned short* __restrict__ WT,
                                                   _Float16* __restrict__ P) {
    __shared__ unsigned short Xs[2][96 * LDSW];
    __shared__ unsigned short Bs[2][64 * LDSW];
    const int bn = blockIdx.x, ks = blockIdx.y, lag = blockIdx.z;
    const int t = threadIdx.x;
    const int wave = t >> 6, lane = t & 63;
    const int l15 = lane & 15, quad = lane >> 4;
    const int mh = wave >> 2, nq = wave & 3;
    const int n0 = bn * 64;
    const int itStart = ks ? KS0 : 0;
    const int itEnd   = ks ? NITER : KS0;

    // staging addresses: X rows 0..63 by all 512, rows 64..95 by t<256 (wave-uniform)
    const int row0 = t >> 3, c80 = (t & 7) * 8;
    const unsigned short* gx0 = X + (size_t)(lag * 96 + row0) * KPAD + c80;
    const unsigned short* gx1 = X + (size_t)(lag * 96 + 64 + row0) * KPAD + c80;
    const unsigned short* gb0 = WT + (size_t)(n0 + row0) * NPAD + c80;
    const int lx0 = row0 * LDSW + c80;
    const int lx1 = (64 + row0) * LDSW + c80;

    int4 xr0, xr1, br0;
    {
        const int k0 = itStart * 64;
        xr0 = *(const int4*)(gx0 + k0);
        if (t < 256) xr1 = *(const int4*)(gx1 + k0);
        br0 = *(const int4*)(gb0 + k0);
    }

    f32x4 acc[3] = {};   // g0=Tout, g1=TN(old), g2=T0(new) partial sums

    for (int it = itStart; it < itEnd; ++it) {
        const int p = (it - itStart) & 1;
        *(int4*)&Xs[p][lx0] = xr0;
        if (t < 256) *(int4*)&Xs[p][lx1] = xr1;
        *(int4*)&Bs[p][lx0] = br0;
        __syncthreads();
        if (it + 1 < itEnd) {
            const int k1 = (it + 1) * 64;
            xr0 = *(const int4*)(gx0 + k1);
            if (t < 256) xr1 = *(const int4*)(gx1 + k1);
            br0 = *(const int4*)(gb0 + k1);
        }
        #pragma unroll
        for (int kh = 0; kh < 2; kh++) {
            bh8 bfrag = *(const bh8*)&Bs[p][(nq * 16 + l15) * LDSW + kh * 32 + quad * 8];
            #pragma unroll
            for (int g = 0; g < 3; g++) {
                bh8 afrag = *(const bh8*)&Xs[p][(mh * 48 + g * 16 + l15) * LDSW + kh * 32 + quad * 8];
                acc[g] = __builtin_amdgcn_mfma_f32_16x16x32_bf16(afrag, bfrag, acc[g], 0, 0, 0);
            }
        }
        // single barrier per iter is safe: write(i+1) targets the buffer read at
        // i-1; every wave's MFMA(i-1) precedes its write(i) -> barrier(i) orders it.
    }

    // store fp16 partials (C/D layout: col=lane&15, row=quad*4+reg)
    const int j = n0 + nq * 16 + l15;
    if (j < NN) {
        _Float16* Pk = P + (size_t)ks * (1152 * NN);
        #pragma unroll
        for (int g = 0; g < 3; g++) {
            int rowb = lag * 96 + mh * 48 + g * 16 + quad * 4;
            #pragma unroll
            for (int r = 0; r < 4; r++)
                Pk[(size_t)(rowb + r) * NN + j] = (_Float16)acc[g][r];
        }
    }
}

// ---- combine: sum fp16 split-K partials, tanh, coefficients, write out ----
// One thread = 4 consecutive j (8B h4 loads; 200%4==0 so the j%200 group never wraps).
__global__ __launch_bounds__(256) void combine_kernel(const _Float16* __restrict__ P,
                                                      const float* __restrict__ coef,
                                                      const float* __restrict__ lambd,
                                                      const float* __restrict__ l,
                                                      float* __restrict__ out) {
    int idx = blockIdx.x * 256 + threadIdx.x;        // 0..115199
    if (idx >= BB * LAG1 * (NN / 4)) return;
    int j4 = idx % (NN / 4);
    int t2 = idx / (NN / 4);
    int lag = t2 % LAG1, b = t2 / LAG1;
    int j = j4 * 4;
    int base = lag * 96 + (b >> 4) * 48 + (b & 15);
    const _Float16* P1 = P + (size_t)1152 * NN;
    h4 s0a = *(const h4*)&P[(size_t)base * NN + j];
    h4 s0b = *(const h4*)&P1[(size_t)base * NN + j];
    h4 s1a = *(const h4*)&P[(size_t)(base + 16) * NN + j];
    h4 s1b = *(const h4*)&P1[(size_t)(base + 16) * NN + j];
    h4 s2a = *(const h4*)&P[(size_t)(base + 32) * NN + j];
    h4 s2b = *(const h4*)&P1[(size_t)(base + 32) * NN + j];
    int jm = j % 200;
    float4 lv  = *(const float4*)&l[lag * 200 + jm];
    float4 lam = *(const float4*)&lambd[lag * 200 + jm];
    float e0 = coef[lag], c2 = coef[12 + lag], ib = coef[24 + lag];
    float4 o;
    {
        float s0 = (float)s0a[0] + (float)s0b[0], s1 = (float)s1a[0] + (float)s1b[0], s2 = (float)s2a[0] + (float)s2b[0];
        o.x = lam.x * ib * (e0 * tanhf(-s0) + 3.0f * lv.x * (tanhf(-s2) + c2 * tanhf(-s1)));
        s0 = (float)s0a[1] + (float)s0b[1]; s1 = (float)s1a[1] + (float)s1b[1]; s2 = (float)s2a[1] + (float)s2b[1];
        o.y = lam.y * ib * (e0 * tanhf(-s0) + 3.0f * lv.y * (tanhf(-s2) + c2 * tanhf(-s1)));
        s0 = (float)s0a[2] + (float)s0b[2]; s1 = (float)s1a[2] + (float)s1b[2]; s2 = (float)s2a[2] + (float)s2b[2];
        o.z = lam.z * ib * (e0 * tanhf(-s0) + 3.0f * lv.z * (tanhf(-s2) + c2 * tanhf(-s1)));
        s0 = (float)s0a[3] + (float)s0b[3]; s1 = (float)s1a[3] + (float)s1b[3]; s2 = (float)s2a[3] + (float)s2b[3];
        o.w = lam.w * ib * (e0 * tanhf(-s0) + 3.0f * lv.w * (tanhf(-s2) + c2 * tanhf(-s1)));
    }
    *(float4*)&out[(size_t)(b * LAG1 + lag) * NN + j] = o;
}

extern "C" void kernel_launch(void* const* d_in, const int* in_sizes, int n_in,
                              void* d_out, int out_size, void* d_ws, size_t ws_size,
                              hipStream_t stream) {
    const float* A     = (const float*)d_in[0];
    const float* WW    = (const float*)d_in[1];
    const float* TI    = (const float*)d_in[2];
    const float* alpha = (const float*)d_in[3];
    const float* fract = (const float*)d_in[4];
    const float* lambd = (const float*)d_in[5];
    const float* l     = (const float*)d_in[6];
    float* out = (float*)d_out;

    unsigned short* X  = (unsigned short*)d_ws;        // 1152*1216 bf16
    unsigned short* WT = X + 1152 * KPAD;              // 1216*1216 bf16
    _Float16* P = (_Float16*)(WT + (size_t)NPAD * NPAD); // 2 * 1152*1200 fp16 partials
    float* coef = (float*)(P + (size_t)2 * 1152 * NN);   // 36 f32

    prep_kernel<<<PREP_BLOCKS, 256, 0, stream>>>(A, TI, WW, alpha, fract, X, WT, coef);
    gemm_splitk<<<dim3(19, 2, LAG1), 512, 0, stream>>>(X, WT, P);
    combine_kernel<<<(BB * LAG1 * (NN / 4) + 255) / 256, 256, 0, stream>>>(P, coef, lambd, l, out);
}

// Round 10
// 104.062 us; speedup vs baseline: 2.4416x; 1.0050x over previous
//
#include <hip/hip_runtime.h>
#include <math.h>

#define PI_F 3.14159265358979323846f

typedef __attribute__((ext_vector_type(8))) short bh8;    // 8 bf16 in 4 VGPRs
typedef __attribute__((ext_vector_type(4))) float f32x4;  // MFMA accumulator
typedef __attribute__((ext_vector_type(4))) _Float16 h4;  // 4 fp16 = 8B

#define LAG1 12      // LAG-1
#define BB   32
#define NN   1200
#define KPAD 1216    // 1200 padded to 19*64
#define NPAD 1216
#define NITER 19     // KPAD / 64
#define NSPLIT 3     // split-K slices: 7/6/6 iters
#define LDSW  72     // LDS row stride in shorts — 144B, 16B-aligned (70 broke b128 alignment)

// X row layout (interleaved for in-register group fusion):
//   row = lag*96 + (b>>4)*48 + g*16 + (b&15),  g: 0=A(Tout) 1=old(TN) 2=new(T0)

// prep block ranges
#define ROW_I4 (KPAD / 8)          // 152 int4 per X row
#define PA_BLK 228                 // A copy: 384 rows * 152 int4 / 256
#define PB_BLK 150                 // TI gather: 32*1200 / 256
#define PD_BLK 6                   // zero-pad g1/g2 rows cols 1200..1215
#define PC_BLK 361                 // WT transpose: 19*19 tiles of 64x64
#define PE_BLK 1                   // coef
#define PREP_BLOCKS (PA_BLK + PB_BLK + PD_BLK + PC_BLK + PE_BLK)

__device__ __forceinline__ unsigned short f2bf(float f) {
    unsigned int u = __float_as_uint(f);
    u = (u + 0x7fffu + ((u >> 16) & 1u)) >> 16;
    return (unsigned short)u;
}

__device__ __forceinline__ float gamma_fn_dev(float x) {
    if (x > 0.0f) return expf(lgammaf(x));
    return PI_F / (sinf(PI_F * x) * expf(lgammaf(1.0f - x)));
}

// ---- prep: X stack (interleaved rows) + pads + WT transpose + coefs ----
__global__ __launch_bounds__(256) void prep_kernel(const float* __restrict__ A,
                                                   const float* __restrict__ TI,
                                                   const float* __restrict__ WW,
                                                   const float* __restrict__ alpha,
                                                   const float* __restrict__ fract,
                                                   unsigned short* __restrict__ X,
                                                   unsigned short* __restrict__ WT,
                                                   float* __restrict__ coef) {
    __shared__ float tile[64][65];           // 16.6 KB; stride 65 -> conflict-free T-reads
    const int bid = blockIdx.x;
    const int t = threadIdx.x;

    if (bid < PA_BLK) {
        // part A: A[lag*32+b, k] -> X row lag*96 + (b>>4)*48 + (b&15); float4 loads
        int idx = bid * 256 + t;                 // 0..58367
        int ra = idx / ROW_I4;                   // 0..383 (= lag*32+b)
        int c8 = idx - ra * ROW_I4;              // 0..151
        int k = c8 * 8;                          // 1200 % 8 == 0: group fully in or out
        int row = (ra >> 5) * 96 + ((ra >> 4) & 1) * 48 + (ra & 15);
        unsigned short v[8];
        if (k < NN) {
            float4 f0 = *(const float4*)&A[ra * NN + k];
            float4 f1 = *(const float4*)&A[ra * NN + k + 4];
            v[0] = f2bf(f0.x); v[1] = f2bf(f0.y); v[2] = f2bf(f0.z); v[3] = f2bf(f0.w);
            v[4] = f2bf(f1.x); v[5] = f2bf(f1.y); v[6] = f2bf(f1.z); v[7] = f2bf(f1.w);
        } else {
            #pragma unroll
            for (int u = 0; u < 8; u++) v[u] = 0;
        }
        *(int4*)&X[row * KPAD + k] = *(int4*)v;
    } else if (bid < PA_BLK + PB_BLK) {
        // part B: TI gather; thread = (b, i)
        int idx = (bid - PA_BLK) * 256 + t;      // 0..38399
        int b = idx / NN, i = idx - b * NN;
        const float* p = TI + (size_t)(b * NN + i) * 26 + 1;  // [...,lg,1]
        float vals[13];
        #pragma unroll
        for (int lg = 0; lg < 13; lg++) vals[lg] = p[lg * 2];
        int rbase = (b >> 4) * 48 + (b & 15);
        #pragma unroll
        for (int lag = 0; lag < LAG1; lag++) {
            X[(lag * 96 + rbase + 16) * KPAD + i] = f2bf(vals[lag]);      // g1 old -> TN
            X[(lag * 96 + rbase + 32) * KPAD + i] = f2bf(vals[lag + 1]);  // g2 new -> T0
        }
    } else if (bid < PA_BLK + PB_BLK + PD_BLK) {
        // part D: zero-pad cols 1200..1215 for the 768 g1/g2 rows
        int idx = (bid - PA_BLK - PB_BLK) * 256 + t;  // 0..1535
        if (idx < 768 * 2) {
            int pr = idx >> 1, h = idx & 1;
            int lag = pr / 64, rem = pr - lag * 64;
            int half = rem >> 5, gi = (rem >> 4) & 1, b16 = rem & 15;
            int row = lag * 96 + half * 48 + 16 + gi * 16 + b16;
            int4 z = {0, 0, 0, 0};
            *(int4*)&X[row * KPAD + 1200 + h * 8] = z;
        }
    } else if (bid < PA_BLK + PB_BLK + PD_BLK + PC_BLK) {
        // part C: WT[j*NPAD+i] = bf16(WW[i*NN+j]), 64x64 tiles, vectorized both sides
        int cb = bid - (PA_BLK + PB_BLK + PD_BLK);
        int bx = cb % 19, by = cb / 19;
        int i0 = by * 64, j0 = bx * 64;
        // load: thread t -> row r=t>>2 (64 rows), col group (t&3)*16; 4 guarded float4
        {
            int r = t >> 2, cg = (t & 3) * 16;
            int i = i0 + r;
            #pragma unroll
            for (int g = 0; g < 4; g++) {
                int j = j0 + cg + g * 4;         // 1200 % 4 == 0: float4 fully in or out
                float4 f = {0.f, 0.f, 0.f, 0.f};
                if (i < NN && j + 3 < NN) f = *(const float4*)&WW[(size_t)i * NN + j];
                tile[r][cg + g * 4 + 0] = f.x;
                tile[r][cg + g * 4 + 1] = f.y;
                tile[r][cg + g * 4 + 2] = f.z;
                tile[r][cg + g * 4 + 3] = f.w;
            }
        }
        __syncthreads();
        // store transposed: thread t -> out row j=j0+(t>>2), i group (t&3)*16; 2 int4
        {
            int j = j0 + (t >> 2), ig = (t & 3) * 16;
            unsigned short v[16];
            #pragma unroll
            for (int u = 0; u < 16; u++) v[u] = f2bf(tile[ig + u][t >> 2]);
            *(int4*)&WT[(size_t)j * NPAD + i0 + ig]     = *(int4*)&v[0];
            *(int4*)&WT[(size_t)j * NPAD + i0 + ig + 8] = *(int4*)&v[8];
        }
    } else {
        // part E: per-lag coefficients
        int lag = t;
        if (lag < LAG1) {
            float a = alpha[lag], f = fract[lag];
            float ga1 = expf(lgammaf(a + 1.0f));
            float belta = 0.0f;
            const float gk[4] = {1.0f, 1.0f, 2.0f, 6.0f};
            #pragma unroll
            for (int kk = 0; kk < 4; kk++)
                belta += ga1 / (gk[kk] * gamma_fn_dev(a - (float)kk + 1.0f));
            coef[lag]      = 2.0f * powf(3.0f, f);                  // e0
            coef[12 + lag] = ga1 / (6.0f * gamma_fn_dev(a - 2.0f)); // c2
            coef[24 + lag] = 1.0f / belta;                          // 1/belta
        }
    }
}

// ---- split-K GEMM: 512 threads, 8 waves; wave = (mh = b-half, nq = 16-col slice) ----
// Block (bn, ks, lag); ks slices K-iters {0..6}/{7..12}/{13..18}. R5's proven K-loop
// body (runtime trip count; single barrier/iter). fp16 raw partials to P[ks].
__global__ __launch_bounds__(512) void gemm_splitk(const unsigned short* __restrict__ X,
                                                   const unsigned short* __restrict__ WT,
                                                   _Float16* __restrict__ P) {
    __shared__ unsigned short Xs[2][96 * LDSW];
    __shared__ unsigned short Bs[2][64 * LDSW];
    const int bn = blockIdx.x, ks = blockIdx.y, lag = blockIdx.z;
    const int t = threadIdx.x;
    const int wave = t >> 6, lane = t & 63;
    const int l15 = lane & 15, quad = lane >> 4;
    const int mh = wave >> 2, nq = wave & 3;
    const int n0 = bn * 64;
    const int itStart = (ks == 0) ? 0 : (ks == 1 ? 7 : 13);
    const int itEnd   = (ks == 0) ? 7 : (ks == 1 ? 13 : NITER);

    // staging addresses: X rows 0..63 by all 512, rows 64..95 by t<256 (wave-uniform)
    const int row0 = t >> 3, c80 = (t & 7) * 8;
    const unsigned short* gx0 = X + (size_t)(lag * 96 + row0) * KPAD + c80;
    const unsigned short* gx1 = X + (size_t)(lag * 96 + 64 + row0) * KPAD + c80;
    const unsigned short* gb0 = WT + (size_t)(n0 + row0) * NPAD + c80;
    const int lx0 = row0 * LDSW + c80;
    const int lx1 = (64 + row0) * LDSW + c80;

    int4 xr0, xr1, br0;
    {
        const int k0 = itStart * 64;
        xr0 = *(const int4*)(gx0 + k0);
        if (t < 256) xr1 = *(const int4*)(gx1 + k0);
        br0 = *(const int4*)(gb0 + k0);
    }

    f32x4 acc[3] = {};   // g0=Tout, g1=TN(old), g2=T0(new) partial sums

    for (int it = itStart; it < itEnd; ++it) {
        const int p = (it - itStart) & 1;
        *(int4*)&Xs[p][lx0] = xr0;
        if (t < 256) *(int4*)&Xs[p][lx1] = xr1;
        *(int4*)&Bs[p][lx0] = br0;
        __syncthreads();
        if (it + 1 < itEnd) {
            const int k1 = (it + 1) * 64;
            xr0 = *(const int4*)(gx0 + k1);
            if (t < 256) xr1 = *(const int4*)(gx1 + k1);
            br0 = *(const int4*)(gb0 + k1);
        }
        #pragma unroll
        for (int kh = 0; kh < 2; kh++) {
            bh8 bfrag = *(const bh8*)&Bs[p][(nq * 16 + l15) * LDSW + kh * 32 + quad * 8];
            #pragma unroll
            for (int g = 0; g < 3; g++) {
                bh8 afrag = *(const bh8*)&Xs[p][(mh * 48 + g * 16 + l15) * LDSW + kh * 32 + quad * 8];
                acc[g] = __builtin_amdgcn_mfma_f32_16x16x32_bf16(afrag, bfrag, acc[g], 0, 0, 0);
            }
        }
        // single barrier per iter is safe: write(i+1) targets the buffer read at
        // i-1; every wave's MFMA(i-1) precedes its write(i) -> barrier(i) orders it.
    }

    // store fp16 partials (C/D layout: col=lane&15, row=quad*4+reg)
    const int j = n0 + nq * 16 + l15;
    if (j < NN) {
        _Float16* Pk = P + (size_t)ks * (1152 * NN);
        #pragma unroll
        for (int g = 0; g < 3; g++) {
            int rowb = lag * 96 + mh * 48 + g * 16 + quad * 4;
            #pragma unroll
            for (int r = 0; r < 4; r++)
                Pk[(size_t)(rowb + r) * NN + j] = (_Float16)acc[g][r];
        }
    }
}

// ---- combine: sum 3 fp16 split-K partials, tanh, coefficients, write out ----
// One thread = 4 consecutive j (8B h4 loads; 200%4==0 so the j%200 group never wraps).
__global__ __launch_bounds__(256) void combine_kernel(const _Float16* __restrict__ P,
                                                      const float* __restrict__ coef,
                                                      const float* __restrict__ lambd,
                                                      const float* __restrict__ l,
                                                      float* __restrict__ out) {
    int idx = blockIdx.x * 256 + threadIdx.x;
    if (idx >= BB * LAG1 * (NN / 4)) return;
    int j4 = idx % (NN / 4);
    int t2 = idx / (NN / 4);
    int lag = t2 % LAG1, b = t2 / LAG1;
    int j = j4 * 4;
    int base = lag * 96 + (b >> 4) * 48 + (b & 15);
    const _Float16* P1 = P + (size_t)1152 * NN;
    const _Float16* P2 = P + (size_t)2 * 1152 * NN;
    float s0[4], s1[4], s2[4];
    {
        h4 a0 = *(const h4*)&P[(size_t)base * NN + j];
        h4 b0 = *(const h4*)&P1[(size_t)base * NN + j];
        h4 c0 = *(const h4*)&P2[(size_t)base * NN + j];
        h4 a1 = *(const h4*)&P[(size_t)(base + 16) * NN + j];
        h4 b1 = *(const h4*)&P1[(size_t)(base + 16) * NN + j];
        h4 c1 = *(const h4*)&P2[(size_t)(base + 16) * NN + j];
        h4 a2 = *(const h4*)&P[(size_t)(base + 32) * NN + j];
        h4 b2 = *(const h4*)&P1[(size_t)(base + 32) * NN + j];
        h4 c2v = *(const h4*)&P2[(size_t)(base + 32) * NN + j];
        #pragma unroll
        for (int u = 0; u < 4; u++) {
            s0[u] = (float)a0[u] + (float)b0[u] + (float)c0[u];
            s1[u] = (float)a1[u] + (float)b1[u] + (float)c1[u];
            s2[u] = (float)a2[u] + (float)b2[u] + (float)c2v[u];
        }
    }
    int jm = j % 200;
    float4 lv  = *(const float4*)&l[lag * 200 + jm];
    float4 lam = *(const float4*)&lambd[lag * 200 + jm];
    float e0 = coef[lag], c2 = coef[12 + lag], ib = coef[24 + lag];
    float lvv[4] = {lv.x, lv.y, lv.z, lv.w};
    float lmm[4] = {lam.x, lam.y, lam.z, lam.w};
    float4 o;
    float ov[4];
    #pragma unroll
    for (int u = 0; u < 4; u++)
        ov[u] = lmm[u] * ib * (e0 * tanhf(-s0[u]) + 3.0f * lvv[u] * (tanhf(-s2[u]) + c2 * tanhf(-s1[u])));
    o.x = ov[0]; o.y = ov[1]; o.z = ov[2]; o.w = ov[3];
    *(float4*)&out[(size_t)(b * LAG1 + lag) * NN + j] = o;
}

extern "C" void kernel_launch(void* const* d_in, const int* in_sizes, int n_in,
                              void* d_out, int out_size, void* d_ws, size_t ws_size,
                              hipStream_t stream) {
    const float* A     = (const float*)d_in[0];
    const float* WW    = (const float*)d_in[1];
    const float* TI    = (const float*)d_in[2];
    const float* alpha = (const float*)d_in[3];
    const float* fract = (const float*)d_in[4];
    const float* lambd = (const float*)d_in[5];
    const float* l     = (const float*)d_in[6];
    float* out = (float*)d_out;

    unsigned short* X  = (unsigned short*)d_ws;        // 1152*1216 bf16
    unsigned short* WT = X + 1152 * KPAD;              // 1216*1216 bf16
    _Float16* P = (_Float16*)(WT + (size_t)NPAD * NPAD); // 3 * 1152*1200 fp16 partials
    float* coef = (float*)(P + (size_t)NSPLIT * 1152 * NN); // 36 f32

    prep_kernel<<<PREP_BLOCKS, 256, 0, stream>>>(A, TI, WW, alpha, fract, X, WT, coef);
    gemm_splitk<<<dim3(19, NSPLIT, LAG1), 512, 0, stream>>>(X, WT, P);
    combine_kernel<<<(BB * LAG1 * (NN / 4) + 255) / 256, 256, 0, stream>>>(P, coef, lambd, l, out);
}